// Round 2
// baseline (139.540 us; speedup 1.0000x reference)
//
#include <hip/hip_runtime.h>

#define NH 8
#define ND 64
#define NM 32
#define NCH 64   // chunk size C
#define NC 16    // num chunks
#define NL 1024

__device__ __forceinline__ float wave_reduce_sum(float v) {
#pragma unroll
    for (int m = 1; m <= 32; m <<= 1)
        v += __shfl_xor(v, m, 64);
    return v;
}

// ---------------- Kernel 1: intra-chunk scan -> totalA, finalH ----------------
__global__ __launch_bounds__(64) void intra_kernel(
    const float* __restrict__ A_bar, const float* __restrict__ K,
    const float* __restrict__ V, const float* __restrict__ beta,
    float* __restrict__ totalA, float* __restrict__ finalH)
{
    const int bid = blockIdx.x;            // (g*NH + hh)*NM + m
    const int m  = bid & (NM - 1);
    const int hh = (bid >> 5) & (NH - 1);
    const int g  = bid >> 8;
    const int lane = threadIdx.x;

    float hr = 0.f, hi = 0.f;
    float cr = 1.f, ci = 0.f;              // running cumprod of a (complex)
    const int base_l = g * NCH;

    for (int t = 0; t < NCH; ++t) {
        const int l = base_l + t;
        const int row = (l * NH + hh) * 64;      // A_bar/V/K rows all 64 wide
        const float kd  = K[row + lane];
        const float are = A_bar[row + 2 * m];
        const float aim = A_bar[row + 2 * m + 1];
        const float vre = V[row + 2 * m];
        const float vim = V[row + 2 * m + 1];
        const float b   = beta[l * NH + hh];

        const float hkr = wave_reduce_sum(hr * kd);
        const float hki = wave_reduce_sum(hi * kd);
        const float bk  = b * kd;
        const float tr  = hr - bk * hkr;
        const float ti  = hi - bk * hki;
        hr = are * tr - aim * ti + bk * vre;
        hi = are * ti + aim * tr + bk * vim;

        const float ncr = cr * are - ci * aim;
        ci = cr * aim + ci * are;
        cr = ncr;
    }

    const int fidx = ((g * NH + hh) * NM + m) * ND + lane;
    finalH[2 * fidx]     = hr;
    finalH[2 * fidx + 1] = hi;
    if (lane == 0) {
        const int tix = (g * NH + hh) * NM + m;
        totalA[2 * tix]     = cr;
        totalA[2 * tix + 1] = ci;
    }
}

// ---------------- Kernel 2: inter-chunk serial scan -> s_in ----------------
__global__ __launch_bounds__(256) void inter_kernel(
    const float* __restrict__ totalA, const float* __restrict__ finalH,
    float* __restrict__ s_in)
{
    const int tid = blockIdx.x * 256 + threadIdx.x;  // (hh*NM+m)*ND + d
    const int d  = tid & 63;
    const int hm = tid >> 6;                         // hh*NM + m, 0..255
    float sr = 0.f, si = 0.f;
#pragma unroll
    for (int g = 0; g < NC; ++g) {
        const int e    = g * 256 + hm;               // (g*NH*NM + hm)
        const int fidx = e * ND + d;
        s_in[2 * fidx]     = sr;
        s_in[2 * fidx + 1] = si;
        const float ar = totalA[2 * e];
        const float ai = totalA[2 * e + 1];
        const float fr = finalH[2 * fidx];
        const float fi = finalH[2 * fidx + 1];
        const float nsr = ar * sr - ai * si + fr;
        si = ar * si + ai * sr + fi;
        sr = nsr;
    }
}

// ---------------- Kernel 3: fused intra recompute + correction -> Y ----------------
__global__ __launch_bounds__(64) void final_kernel(
    const float* __restrict__ A_bar, const float* __restrict__ K,
    const float* __restrict__ V, const float* __restrict__ beta,
    const float* __restrict__ s_in, float* __restrict__ Y)
{
    const int bid = blockIdx.x;
    const int m  = bid & (NM - 1);
    const int hh = (bid >> 5) & (NH - 1);
    const int g  = bid >> 8;
    const int lane = threadIdx.x;

    float hr = 0.f, hi = 0.f;
    const int fidx = ((g * NH + hh) * NM + m) * ND + lane;
    float zr = s_in[2 * fidx];
    float zi = s_in[2 * fidx + 1];
    float cr = 1.f, ci = 0.f;
    const int base_l = g * NCH;

    for (int t = 0; t < NCH; ++t) {
        const int l = base_l + t;
        const int row = (l * NH + hh) * 64;
        const float kd  = K[row + lane];
        const float are = A_bar[row + 2 * m];
        const float aim = A_bar[row + 2 * m + 1];
        const float vre = V[row + 2 * m];
        const float vim = V[row + 2 * m + 1];
        const float b   = beta[l * NH + hh];

        const float hkr = wave_reduce_sum(hr * kd);
        const float hki = wave_reduce_sum(hi * kd);
        const float zkr = wave_reduce_sum(zr * kd);
        const float zki = wave_reduce_sum(zi * kd);
        const float bk  = b * kd;

        const float tr = hr - bk * hkr;
        const float ti = hi - bk * hki;
        hr = are * tr - aim * ti + bk * vre;
        hi = are * ti + aim * tr + bk * vim;

        zr -= bk * zkr;
        zi -= bk * zki;

        const float ncr = cr * are - ci * aim;
        ci = cr * aim + ci * are;
        cr = ncr;

        const float yr = hr + cr * zr - ci * zi;
        const float yi = hi + cr * zi + ci * zr;

        // Y[b,l,h,2m,d] = Re, Y[b,l,h,2m+1,d] = Im  (interleaved rows!)
        const int ybase = (l * NH + hh) * (2 * NM) * ND + lane;
        Y[ybase + (2 * m) * ND]     = yr;
        Y[ybase + (2 * m + 1) * ND] = yi;
    }
}

extern "C" void kernel_launch(void* const* d_in, const int* in_sizes, int n_in,
                              void* d_out, int out_size, void* d_ws, size_t ws_size,
                              hipStream_t stream) {
    const float* A_bar = (const float*)d_in[0];
    const float* K     = (const float*)d_in[1];
    const float* V     = (const float*)d_in[2];
    const float* beta  = (const float*)d_in[3];
    float* Y = (float*)d_out;

    // workspace layout (floats)
    float* ws = (float*)d_ws;
    float* totalA = ws;                         // 16*8*32*2      = 8192
    float* finalH = ws + 8192;                  // 16*8*32*64*2   = 2097152
    float* s_in   = ws + 8192 + 2097152;        // 2097152

    const int nblk = NC * NH * NM;              // 4096
    intra_kernel<<<nblk, 64, 0, stream>>>(A_bar, K, V, beta, totalA, finalH);
    inter_kernel<<<(NH * NM * ND) / 256, 256, 0, stream>>>(totalA, finalH, s_in);
    final_kernel<<<nblk, 64, 0, stream>>>(A_bar, K, V, beta, s_in, Y);
}

// Round 3
// 83.215 us; speedup vs baseline: 1.6769x; 1.6769x over previous
//
#include <hip/hip_runtime.h>

#define NH 8
#define ND 64
#define NM 32
#define NCH 64   // chunk size C
#define NC 16    // num chunks

// Full-wave (64-lane) sum reduction using DPP on the VALU pipe:
// row_shr 1/2/4/8 -> each 16-lane row's lane15 holds the row sum;
// row_bcast:15 (rows 1,3) then row_bcast:31 (rows 2,3) -> lane 63 = total.
// v_readlane lane 63 -> SGPR, broadcast to all lanes as a uniform value.
__device__ __forceinline__ float wave_sum_bcast(float x) {
    float s = x;
    s += __int_as_float(__builtin_amdgcn_update_dpp(0, __float_as_int(s), 0x111, 0xf, 0xf, false));
    s += __int_as_float(__builtin_amdgcn_update_dpp(0, __float_as_int(s), 0x112, 0xf, 0xf, false));
    s += __int_as_float(__builtin_amdgcn_update_dpp(0, __float_as_int(s), 0x114, 0xf, 0xf, false));
    s += __int_as_float(__builtin_amdgcn_update_dpp(0, __float_as_int(s), 0x118, 0xf, 0xf, false));
    s += __int_as_float(__builtin_amdgcn_update_dpp(0, __float_as_int(s), 0x142, 0xa, 0xf, false));
    s += __int_as_float(__builtin_amdgcn_update_dpp(0, __float_as_int(s), 0x143, 0xc, 0xf, false));
    return __int_as_float(__builtin_amdgcn_readlane(__float_as_int(s), 63));
}

// ---------------- Kernel 1: intra-chunk scan -> totalA, finalH ----------------
__global__ __launch_bounds__(256) void intra_kernel(
    const float* __restrict__ A_bar, const float* __restrict__ K,
    const float* __restrict__ V, const float* __restrict__ beta,
    float* __restrict__ totalA, float* __restrict__ finalH)
{
    const int w  = blockIdx.x * 4 + (threadIdx.x >> 6);  // (g*NH + hh)*NM + m
    const int m  = w & (NM - 1);
    const int hh = (w >> 5) & (NH - 1);
    const int g  = w >> 8;
    const int lane = threadIdx.x & 63;

    float hr = 0.f, hi = 0.f;
    float cr = 1.f, ci = 0.f;
    const int base_l = g * NCH;

#pragma unroll 4
    for (int t = 0; t < NCH; ++t) {
        const int l = base_l + t;
        const int row = (l * NH + hh) * 64;
        const float  kd = K[row + lane];
        const float2 a2 = *(const float2*)(A_bar + row + 2 * m);
        const float2 v2 = *(const float2*)(V + row + 2 * m);
        const float  b  = beta[l * NH + hh];

        const float hkr = wave_sum_bcast(hr * kd);
        const float hki = wave_sum_bcast(hi * kd);
        const float bk  = b * kd;
        const float tr  = hr - bk * hkr;
        const float ti  = hi - bk * hki;
        hr = a2.x * tr - a2.y * ti + bk * v2.x;
        hi = a2.x * ti + a2.y * tr + bk * v2.y;

        const float ncr = cr * a2.x - ci * a2.y;
        ci = cr * a2.y + ci * a2.x;
        cr = ncr;
    }

    const int fidx = w * ND + lane;
    finalH[2 * fidx]     = hr;
    finalH[2 * fidx + 1] = hi;
    if (lane == 0) {
        totalA[2 * w]     = cr;
        totalA[2 * w + 1] = ci;
    }
}

// ---------------- Kernel 2: inter-chunk serial scan -> s_in ----------------
__global__ __launch_bounds__(256) void inter_kernel(
    const float* __restrict__ totalA, const float* __restrict__ finalH,
    float* __restrict__ s_in)
{
    const int tid = blockIdx.x * 256 + threadIdx.x;  // (hh*NM+m)*ND + d
    const int d  = tid & 63;
    const int hm = tid >> 6;
    float sr = 0.f, si = 0.f;
#pragma unroll
    for (int g = 0; g < NC; ++g) {
        const int e    = g * 256 + hm;
        const int fidx = e * ND + d;
        s_in[2 * fidx]     = sr;
        s_in[2 * fidx + 1] = si;
        const float ar = totalA[2 * e];
        const float ai = totalA[2 * e + 1];
        const float fr = finalH[2 * fidx];
        const float fi = finalH[2 * fidx + 1];
        const float nsr = ar * sr - ai * si + fr;
        si = ar * si + ai * sr + fi;
        sr = nsr;
    }
}

// ---------------- Kernel 3: fused intra recompute + correction -> Y ----------------
__global__ __launch_bounds__(256) void final_kernel(
    const float* __restrict__ A_bar, const float* __restrict__ K,
    const float* __restrict__ V, const float* __restrict__ beta,
    const float* __restrict__ s_in, float* __restrict__ Y)
{
    const int w  = blockIdx.x * 4 + (threadIdx.x >> 6);
    const int m  = w & (NM - 1);
    const int hh = (w >> 5) & (NH - 1);
    const int g  = w >> 8;
    const int lane = threadIdx.x & 63;

    float hr = 0.f, hi = 0.f;
    const int fidx = w * ND + lane;
    float zr = s_in[2 * fidx];
    float zi = s_in[2 * fidx + 1];
    float cr = 1.f, ci = 0.f;
    const int base_l = g * NCH;

#pragma unroll 4
    for (int t = 0; t < NCH; ++t) {
        const int l = base_l + t;
        const int row = (l * NH + hh) * 64;
        const float  kd = K[row + lane];
        const float2 a2 = *(const float2*)(A_bar + row + 2 * m);
        const float2 v2 = *(const float2*)(V + row + 2 * m);
        const float  b  = beta[l * NH + hh];

        const float hkr = wave_sum_bcast(hr * kd);
        const float hki = wave_sum_bcast(hi * kd);
        const float zkr = wave_sum_bcast(zr * kd);
        const float zki = wave_sum_bcast(zi * kd);
        const float bk  = b * kd;

        const float tr = hr - bk * hkr;
        const float ti = hi - bk * hki;
        hr = a2.x * tr - a2.y * ti + bk * v2.x;
        hi = a2.x * ti + a2.y * tr + bk * v2.y;

        zr -= bk * zkr;
        zi -= bk * zki;

        const float ncr = cr * a2.x - ci * a2.y;
        ci = cr * a2.y + ci * a2.x;
        cr = ncr;

        const float yr = hr + cr * zr - ci * zi;
        const float yi = hi + cr * zi + ci * zr;

        // Y[b,l,h,2m,d] = Re, Y[b,l,h,2m+1,d] = Im  (interleaved rows)
        const int ybase = (l * NH + hh) * (2 * NM) * ND + lane;
        Y[ybase + (2 * m) * ND]     = yr;
        Y[ybase + (2 * m + 1) * ND] = yi;
    }
}

extern "C" void kernel_launch(void* const* d_in, const int* in_sizes, int n_in,
                              void* d_out, int out_size, void* d_ws, size_t ws_size,
                              hipStream_t stream) {
    const float* A_bar = (const float*)d_in[0];
    const float* K     = (const float*)d_in[1];
    const float* V     = (const float*)d_in[2];
    const float* beta  = (const float*)d_in[3];
    float* Y = (float*)d_out;

    float* ws = (float*)d_ws;
    float* totalA = ws;                         // 16*8*32*2      = 8192
    float* finalH = ws + 8192;                  // 16*8*32*64*2   = 2097152
    float* s_in   = ws + 8192 + 2097152;        // 2097152

    const int nwave = NC * NH * NM;             // 4096 waves
    intra_kernel<<<nwave / 4, 256, 0, stream>>>(A_bar, K, V, beta, totalA, finalH);
    inter_kernel<<<(NH * NM * ND) / 256, 256, 0, stream>>>(totalA, finalH, s_in);
    final_kernel<<<nwave / 4, 256, 0, stream>>>(A_bar, K, V, beta, s_in, Y);
}

// Round 4
// 82.847 us; speedup vs baseline: 1.6843x; 1.0044x over previous
//
#include <hip/hip_runtime.h>

#define NH 8
#define ND 64
#define NM 32
#define NCH 32   // sub-chunk size (re-chunked from reference's 64; math is associative)
#define NC 32    // num sub-chunks

// Full-wave (64-lane) sum reduction using DPP on the VALU pipe.
__device__ __forceinline__ float wave_sum_bcast(float x) {
    float s = x;
    s += __int_as_float(__builtin_amdgcn_update_dpp(0, __float_as_int(s), 0x111, 0xf, 0xf, false));
    s += __int_as_float(__builtin_amdgcn_update_dpp(0, __float_as_int(s), 0x112, 0xf, 0xf, false));
    s += __int_as_float(__builtin_amdgcn_update_dpp(0, __float_as_int(s), 0x114, 0xf, 0xf, false));
    s += __int_as_float(__builtin_amdgcn_update_dpp(0, __float_as_int(s), 0x118, 0xf, 0xf, false));
    s += __int_as_float(__builtin_amdgcn_update_dpp(0, __float_as_int(s), 0x142, 0xa, 0xf, false));
    s += __int_as_float(__builtin_amdgcn_update_dpp(0, __float_as_int(s), 0x143, 0xc, 0xf, false));
    return __int_as_float(__builtin_amdgcn_readlane(__float_as_int(s), 63));
}

// ---------------- Kernel 1: intra-sub-chunk scan -> totalA, finalH ----------------
__global__ __launch_bounds__(256) void intra_kernel(
    const float* __restrict__ A_bar, const float* __restrict__ K,
    const float* __restrict__ V, const float* __restrict__ beta,
    float* __restrict__ totalA, float* __restrict__ finalH)
{
    const int w  = blockIdx.x * 4 + (threadIdx.x >> 6);  // (g*NH + hh)*NM + m
    const int m  = w & (NM - 1);
    const int hh = (w >> 5) & (NH - 1);
    const int g  = w >> 8;
    const int lane = threadIdx.x & 63;

    float hr = 0.f, hi = 0.f;
    float cr = 1.f, ci = 0.f;
    const int base_l = g * NCH;

#pragma unroll 4
    for (int t = 0; t < NCH; ++t) {
        const int l = base_l + t;
        const int row = (l * NH + hh) * 64;
        const float  kd = K[row + lane];
        const float2 a2 = *(const float2*)(A_bar + row + 2 * m);
        const float2 v2 = *(const float2*)(V + row + 2 * m);
        const float  b  = beta[l * NH + hh];

        const float hkr = wave_sum_bcast(hr * kd);
        const float hki = wave_sum_bcast(hi * kd);
        const float bk  = b * kd;
        const float tr  = hr - bk * hkr;
        const float ti  = hi - bk * hki;
        hr = a2.x * tr - a2.y * ti + bk * v2.x;
        hi = a2.x * ti + a2.y * tr + bk * v2.y;

        const float ncr = cr * a2.x - ci * a2.y;
        ci = cr * a2.y + ci * a2.x;
        cr = ncr;
    }

    const int fidx = w * ND + lane;
    finalH[2 * fidx]     = hr;
    finalH[2 * fidx + 1] = hi;
    if (lane == 0) {
        totalA[2 * w]     = cr;
        totalA[2 * w + 1] = ci;
    }
}

// ---------------- Kernel 2: inter-chunk serial scan, IN PLACE: finalH -> s_in ----------------
__global__ __launch_bounds__(256) void inter_kernel(
    const float* __restrict__ totalA, float* __restrict__ buf /* finalH -> s_in */)
{
    const int tid = blockIdx.x * 256 + threadIdx.x;  // (hh*NM+m)*ND + d
    const int d  = tid & 63;
    const int hm = tid >> 6;                         // 0..255
    float sr = 0.f, si = 0.f;
#pragma unroll
    for (int g = 0; g < NC; ++g) {
        const int e    = g * 256 + hm;               // wave id
        const int fidx = e * ND + d;
        const float fr = buf[2 * fidx];
        const float fi = buf[2 * fidx + 1];
        buf[2 * fidx]     = sr;                      // s_in (state entering chunk g)
        buf[2 * fidx + 1] = si;
        const float ar = totalA[2 * e];
        const float ai = totalA[2 * e + 1];
        const float nsr = ar * sr - ai * si + fr;
        si = ar * si + ai * sr + fi;
        sr = nsr;
    }
}

// ---------------- Kernel 3: fused intra recompute + correction -> Y ----------------
__global__ __launch_bounds__(256) void final_kernel(
    const float* __restrict__ A_bar, const float* __restrict__ K,
    const float* __restrict__ V, const float* __restrict__ beta,
    const float* __restrict__ s_in, float* __restrict__ Y)
{
    const int w  = blockIdx.x * 4 + (threadIdx.x >> 6);
    const int m  = w & (NM - 1);
    const int hh = (w >> 5) & (NH - 1);
    const int g  = w >> 8;
    const int lane = threadIdx.x & 63;

    float hr = 0.f, hi = 0.f;
    const int fidx = w * ND + lane;
    float zr = s_in[2 * fidx];
    float zi = s_in[2 * fidx + 1];
    float cr = 1.f, ci = 0.f;
    const int base_l = g * NCH;

#pragma unroll 4
    for (int t = 0; t < NCH; ++t) {
        const int l = base_l + t;
        const int row = (l * NH + hh) * 64;
        const float  kd = K[row + lane];
        const float2 a2 = *(const float2*)(A_bar + row + 2 * m);
        const float2 v2 = *(const float2*)(V + row + 2 * m);
        const float  b  = beta[l * NH + hh];

        const float hkr = wave_sum_bcast(hr * kd);
        const float hki = wave_sum_bcast(hi * kd);
        const float zkr = wave_sum_bcast(zr * kd);
        const float zki = wave_sum_bcast(zi * kd);
        const float bk  = b * kd;

        const float tr = hr - bk * hkr;
        const float ti = hi - bk * hki;
        hr = a2.x * tr - a2.y * ti + bk * v2.x;
        hi = a2.x * ti + a2.y * tr + bk * v2.y;

        zr -= bk * zkr;
        zi -= bk * zki;

        const float ncr = cr * a2.x - ci * a2.y;
        ci = cr * a2.y + ci * a2.x;
        cr = ncr;

        const float yr = hr + cr * zr - ci * zi;
        const float yi = hi + cr * zi + ci * zr;

        // Y[b,l,h,2m,d] = Re, Y[b,l,h,2m+1,d] = Im
        const int ybase = (l * NH + hh) * (2 * NM) * ND + lane;
        Y[ybase + (2 * m) * ND]     = yr;
        Y[ybase + (2 * m + 1) * ND] = yi;
    }
}

extern "C" void kernel_launch(void* const* d_in, const int* in_sizes, int n_in,
                              void* d_out, int out_size, void* d_ws, size_t ws_size,
                              hipStream_t stream) {
    const float* A_bar = (const float*)d_in[0];
    const float* K     = (const float*)d_in[1];
    const float* V     = (const float*)d_in[2];
    const float* beta  = (const float*)d_in[3];
    float* Y = (float*)d_out;

    float* ws = (float*)d_ws;
    float* totalA = ws;                         // NC*NH*NM*2          = 16384 floats
    float* buf    = ws + 16384;                 // finalH/s_in in place: NC*NH*NM*ND*2 = 1,048,576 floats (4 MB)

    const int nwave = NC * NH * NM;             // 8192 waves
    intra_kernel<<<nwave / 4, 256, 0, stream>>>(A_bar, K, V, beta, totalA, buf);
    inter_kernel<<<(NH * NM * ND) / 256, 256, 0, stream>>>(totalA, buf);
    final_kernel<<<nwave / 4, 256, 0, stream>>>(A_bar, K, V, beta, buf, Y);
}

// Round 5
// 76.275 us; speedup vs baseline: 1.8294x; 1.0862x over previous
//
#include <hip/hip_runtime.h>

#define NH 8
#define ND 64
#define NM 32
#define NCH 32   // sub-chunk size (re-chunked; math is associative)
#define NC 32    // num sub-chunks

// Full-wave (64-lane) sum reduction using DPP on the VALU pipe.
__device__ __forceinline__ float wave_sum_bcast(float x) {
    float s = x;
    s += __int_as_float(__builtin_amdgcn_update_dpp(0, __float_as_int(s), 0x111, 0xf, 0xf, false));
    s += __int_as_float(__builtin_amdgcn_update_dpp(0, __float_as_int(s), 0x112, 0xf, 0xf, false));
    s += __int_as_float(__builtin_amdgcn_update_dpp(0, __float_as_int(s), 0x114, 0xf, 0xf, false));
    s += __int_as_float(__builtin_amdgcn_update_dpp(0, __float_as_int(s), 0x118, 0xf, 0xf, false));
    s += __int_as_float(__builtin_amdgcn_update_dpp(0, __float_as_int(s), 0x142, 0xa, 0xf, false));
    s += __int_as_float(__builtin_amdgcn_update_dpp(0, __float_as_int(s), 0x143, 0xc, 0xf, false));
    return __int_as_float(__builtin_amdgcn_readlane(__float_as_int(s), 63));
}

// Cooperative stage of one (g,hh) chunk into LDS. Block = 256 threads.
// K/A/V rows in global are strided by NH*64 floats for fixed hh.
__device__ __forceinline__ void stage_chunk(
    const float* __restrict__ A_bar, const float* __restrict__ K,
    const float* __restrict__ V, const float* __restrict__ beta,
    int g, int hh,
    float (*K_lds)[ND], float (*A_lds)[ND], float (*V_lds)[ND], float* b_lds)
{
    const int tid = threadIdx.x;              // 256 threads
    const int t   = tid >> 3;                 // 0..31
    const int i   = tid & 7;                  // 0..7  -> 8 floats each
    const int l   = g * NCH + t;
    const int row = (l * NH + hh) * 64;
    // 8 contiguous floats per thread via two float4s
    const float4 k4a = *(const float4*)(K + row + i * 8);
    const float4 k4b = *(const float4*)(K + row + i * 8 + 4);
    const float4 a4a = *(const float4*)(A_bar + row + i * 8);
    const float4 a4b = *(const float4*)(A_bar + row + i * 8 + 4);
    const float4 v4a = *(const float4*)(V + row + i * 8);
    const float4 v4b = *(const float4*)(V + row + i * 8 + 4);
    *(float4*)(&K_lds[t][i * 8])     = k4a;
    *(float4*)(&K_lds[t][i * 8 + 4]) = k4b;
    *(float4*)(&A_lds[t][i * 8])     = a4a;
    *(float4*)(&A_lds[t][i * 8 + 4]) = a4b;
    *(float4*)(&V_lds[t][i * 8])     = v4a;
    *(float4*)(&V_lds[t][i * 8 + 4]) = v4b;
    if (tid < NCH) b_lds[tid] = beta[(g * NCH + tid) * NH + hh];
    __syncthreads();
}

// ---------------- Kernel 1: intra-sub-chunk scan -> totalA, finalH ----------------
__global__ __launch_bounds__(256) void intra_kernel(
    const float* __restrict__ A_bar, const float* __restrict__ K,
    const float* __restrict__ V, const float* __restrict__ beta,
    float* __restrict__ totalA, float* __restrict__ finalH)
{
    __shared__ float K_lds[NCH][ND], A_lds[NCH][ND], V_lds[NCH][ND], b_lds[NCH];
    const int w  = blockIdx.x * 4 + (threadIdx.x >> 6);  // (g*NH + hh)*NM + m
    const int m  = w & (NM - 1);
    const int hh = (w >> 5) & (NH - 1);
    const int g  = w >> 8;
    const int lane = threadIdx.x & 63;

    stage_chunk(A_bar, K, V, beta, g, hh, K_lds, A_lds, V_lds, b_lds);

    float hr = 0.f, hi = 0.f;
    float cr = 1.f, ci = 0.f;

#pragma unroll 4
    for (int t = 0; t < NCH; ++t) {
        const float  kd = K_lds[t][lane];
        const float2 a2 = *(const float2*)(&A_lds[t][2 * m]);
        const float2 v2 = *(const float2*)(&V_lds[t][2 * m]);
        const float  b  = b_lds[t];

        const float hkr = wave_sum_bcast(hr * kd);
        const float hki = wave_sum_bcast(hi * kd);
        const float bk  = b * kd;
        const float tr  = hr - bk * hkr;
        const float ti  = hi - bk * hki;
        hr = a2.x * tr - a2.y * ti + bk * v2.x;
        hi = a2.x * ti + a2.y * tr + bk * v2.y;

        const float ncr = cr * a2.x - ci * a2.y;
        ci = cr * a2.y + ci * a2.x;
        cr = ncr;
    }

    const int fidx = w * ND + lane;
    finalH[2 * fidx]     = hr;
    finalH[2 * fidx + 1] = hi;
    if (lane == 0) {
        totalA[2 * w]     = cr;
        totalA[2 * w + 1] = ci;
    }
}

// ---------------- Kernel 2: inter-chunk serial scan, IN PLACE: finalH -> s_in ----------------
__global__ __launch_bounds__(256) void inter_kernel(
    const float* __restrict__ totalA, float* __restrict__ buf /* finalH -> s_in */)
{
    const int tid = blockIdx.x * 256 + threadIdx.x;  // (hh*NM+m)*ND + d
    const int d  = tid & 63;
    const int hm = tid >> 6;                         // 0..255
    float sr = 0.f, si = 0.f;
#pragma unroll
    for (int g = 0; g < NC; ++g) {
        const int e    = g * 256 + hm;               // wave id
        const int fidx = e * ND + d;
        const float fr = buf[2 * fidx];
        const float fi = buf[2 * fidx + 1];
        buf[2 * fidx]     = sr;                      // s_in (state entering chunk g)
        buf[2 * fidx + 1] = si;
        const float ar = totalA[2 * e];
        const float ai = totalA[2 * e + 1];
        const float nsr = ar * sr - ai * si + fr;
        si = ar * si + ai * sr + fi;
        sr = nsr;
    }
}

// ---------------- Kernel 3: fused intra recompute + correction -> Y ----------------
__global__ __launch_bounds__(256) void final_kernel(
    const float* __restrict__ A_bar, const float* __restrict__ K,
    const float* __restrict__ V, const float* __restrict__ beta,
    const float* __restrict__ s_in, float* __restrict__ Y)
{
    __shared__ float K_lds[NCH][ND], A_lds[NCH][ND], V_lds[NCH][ND], b_lds[NCH];
    const int w  = blockIdx.x * 4 + (threadIdx.x >> 6);
    const int m  = w & (NM - 1);
    const int hh = (w >> 5) & (NH - 1);
    const int g  = w >> 8;
    const int lane = threadIdx.x & 63;

    stage_chunk(A_bar, K, V, beta, g, hh, K_lds, A_lds, V_lds, b_lds);

    float hr = 0.f, hi = 0.f;
    const int fidx = w * ND + lane;
    float zr = s_in[2 * fidx];
    float zi = s_in[2 * fidx + 1];
    float cr = 1.f, ci = 0.f;
    const int base_l = g * NCH;

#pragma unroll 4
    for (int t = 0; t < NCH; ++t) {
        const float  kd = K_lds[t][lane];
        const float2 a2 = *(const float2*)(&A_lds[t][2 * m]);
        const float2 v2 = *(const float2*)(&V_lds[t][2 * m]);
        const float  b  = b_lds[t];

        const float hkr = wave_sum_bcast(hr * kd);
        const float hki = wave_sum_bcast(hi * kd);
        const float zkr = wave_sum_bcast(zr * kd);
        const float zki = wave_sum_bcast(zi * kd);
        const float bk  = b * kd;

        const float tr = hr - bk * hkr;
        const float ti = hi - bk * hki;
        hr = a2.x * tr - a2.y * ti + bk * v2.x;
        hi = a2.x * ti + a2.y * tr + bk * v2.y;

        zr -= bk * zkr;
        zi -= bk * zki;

        const float ncr = cr * a2.x - ci * a2.y;
        ci = cr * a2.y + ci * a2.x;
        cr = ncr;

        const float yr = hr + cr * zr - ci * zi;
        const float yi = hi + cr * zi + ci * zr;

        // Y[b,l,h,2m,d] = Re, Y[b,l,h,2m+1,d] = Im  — non-temporal, don't thrash L2
        const int ybase = ((base_l + t) * NH + hh) * (2 * NM) * ND + lane;
        __builtin_nontemporal_store(yr, &Y[ybase + (2 * m) * ND]);
        __builtin_nontemporal_store(yi, &Y[ybase + (2 * m + 1) * ND]);
    }
}

extern "C" void kernel_launch(void* const* d_in, const int* in_sizes, int n_in,
                              void* d_out, int out_size, void* d_ws, size_t ws_size,
                              hipStream_t stream) {
    const float* A_bar = (const float*)d_in[0];
    const float* K     = (const float*)d_in[1];
    const float* V     = (const float*)d_in[2];
    const float* beta  = (const float*)d_in[3];
    float* Y = (float*)d_out;

    float* ws = (float*)d_ws;
    float* totalA = ws;                         // NC*NH*NM*2 = 16384 floats
    float* buf    = ws + 16384;                 // finalH/s_in in place: 1,048,576 floats

    const int nwave = NC * NH * NM;             // 8192 waves
    intra_kernel<<<nwave / 4, 256, 0, stream>>>(A_bar, K, V, beta, totalA, buf);
    inter_kernel<<<(NH * NM * ND) / 256, 256, 0, stream>>>(totalA, buf);
    final_kernel<<<nwave / 4, 256, 0, stream>>>(A_bar, K, V, beta, buf, Y);
}

// Round 6
// 70.055 us; speedup vs baseline: 1.9919x; 1.0888x over previous
//
#include <hip/hip_runtime.h>

#define NH 8
#define ND 64
#define NM 32
#define NCH 32   // sub-chunk size (re-chunked; math is associative)
#define NC 32    // num sub-chunks

// Full-wave (64-lane) sum reduction using DPP on the VALU pipe.
__device__ __forceinline__ float wave_sum_bcast(float x) {
    float s = x;
    s += __int_as_float(__builtin_amdgcn_update_dpp(0, __float_as_int(s), 0x111, 0xf, 0xf, false));
    s += __int_as_float(__builtin_amdgcn_update_dpp(0, __float_as_int(s), 0x112, 0xf, 0xf, false));
    s += __int_as_float(__builtin_amdgcn_update_dpp(0, __float_as_int(s), 0x114, 0xf, 0xf, false));
    s += __int_as_float(__builtin_amdgcn_update_dpp(0, __float_as_int(s), 0x118, 0xf, 0xf, false));
    s += __int_as_float(__builtin_amdgcn_update_dpp(0, __float_as_int(s), 0x142, 0xa, 0xf, false));
    s += __int_as_float(__builtin_amdgcn_update_dpp(0, __float_as_int(s), 0x143, 0xc, 0xf, false));
    return __int_as_float(__builtin_amdgcn_readlane(__float_as_int(s), 63));
}

// Cooperative stage of one (g,hh) chunk into LDS. Block = 256 threads.
__device__ __forceinline__ void stage_chunk(
    const float* __restrict__ A_bar, const float* __restrict__ K,
    const float* __restrict__ V, const float* __restrict__ beta,
    int g, int hh,
    float (*K_lds)[ND], float (*A_lds)[ND], float (*V_lds)[ND], float* b_lds)
{
    const int tid = threadIdx.x;              // 256 threads
    const int t   = tid >> 3;                 // 0..31
    const int i   = tid & 7;                  // 0..7 -> 8 floats each
    const int l   = g * NCH + t;
    const int row = (l * NH + hh) * 64;
    const float4 k4a = *(const float4*)(K + row + i * 8);
    const float4 k4b = *(const float4*)(K + row + i * 8 + 4);
    const float4 a4a = *(const float4*)(A_bar + row + i * 8);
    const float4 a4b = *(const float4*)(A_bar + row + i * 8 + 4);
    const float4 v4a = *(const float4*)(V + row + i * 8);
    const float4 v4b = *(const float4*)(V + row + i * 8 + 4);
    *(float4*)(&K_lds[t][i * 8])     = k4a;
    *(float4*)(&K_lds[t][i * 8 + 4]) = k4b;
    *(float4*)(&A_lds[t][i * 8])     = a4a;
    *(float4*)(&A_lds[t][i * 8 + 4]) = a4b;
    *(float4*)(&V_lds[t][i * 8])     = v4a;
    *(float4*)(&V_lds[t][i * 8 + 4]) = v4b;
    if (tid < NCH) b_lds[tid] = beta[(g * NCH + tid) * NH + hh];
    __syncthreads();
}

// ---------------- Kernel 1: intra scan, 2 m-rows per wave -> totalA, finalH ----------------
__global__ __launch_bounds__(256) void intra_kernel(
    const float* __restrict__ A_bar, const float* __restrict__ K,
    const float* __restrict__ V, const float* __restrict__ beta,
    float* __restrict__ totalA, float* __restrict__ finalH)
{
    __shared__ float K_lds[NCH][ND], A_lds[NCH][ND], V_lds[NCH][ND], b_lds[NCH];
    const int w  = blockIdx.x * 4 + (threadIdx.x >> 6);  // pair-wave id
    const int p  = w & 15;                               // m0 = p, m1 = p+16
    const int hh = (w >> 4) & (NH - 1);
    const int g  = w >> 7;
    const int lane = threadIdx.x & 63;

    stage_chunk(A_bar, K, V, beta, g, hh, K_lds, A_lds, V_lds, b_lds);

    float hr0 = 0.f, hi0 = 0.f, hr1 = 0.f, hi1 = 0.f;
    float cr0 = 1.f, ci0 = 0.f, cr1 = 1.f, ci1 = 0.f;

#pragma unroll 4
    for (int t = 0; t < NCH; ++t) {
        const float  kd  = K_lds[t][lane];
        const float  b   = b_lds[t];
        const float2 a0  = *(const float2*)(&A_lds[t][2 * p]);
        const float2 v0  = *(const float2*)(&V_lds[t][2 * p]);
        const float2 a1  = *(const float2*)(&A_lds[t][2 * (p + 16)]);
        const float2 v1  = *(const float2*)(&V_lds[t][2 * (p + 16)]);
        const float  bk  = b * kd;

        const float hkr0 = wave_sum_bcast(hr0 * kd);
        const float hki0 = wave_sum_bcast(hi0 * kd);
        const float hkr1 = wave_sum_bcast(hr1 * kd);
        const float hki1 = wave_sum_bcast(hi1 * kd);

        const float tr0 = hr0 - bk * hkr0, ti0 = hi0 - bk * hki0;
        hr0 = a0.x * tr0 - a0.y * ti0 + bk * v0.x;
        hi0 = a0.x * ti0 + a0.y * tr0 + bk * v0.y;
        const float tr1 = hr1 - bk * hkr1, ti1 = hi1 - bk * hki1;
        hr1 = a1.x * tr1 - a1.y * ti1 + bk * v1.x;
        hi1 = a1.x * ti1 + a1.y * tr1 + bk * v1.y;

        float n;
        n = cr0 * a0.x - ci0 * a0.y; ci0 = cr0 * a0.y + ci0 * a0.x; cr0 = n;
        n = cr1 * a1.x - ci1 * a1.y; ci1 = cr1 * a1.y + ci1 * a1.x; cr1 = n;
    }

    const int base = (g * NH + hh) * NM;
    const int f0 = (base + p) * ND + lane;
    const int f1 = (base + p + 16) * ND + lane;
    finalH[2 * f0]     = hr0;  finalH[2 * f0 + 1] = hi0;
    finalH[2 * f1]     = hr1;  finalH[2 * f1 + 1] = hi1;
    if (lane == 0) {
        totalA[2 * (base + p)]          = cr0;
        totalA[2 * (base + p) + 1]      = ci0;
        totalA[2 * (base + p + 16)]     = cr1;
        totalA[2 * (base + p + 16) + 1] = ci1;
    }
}

// ---------------- Kernel 2: inter-chunk serial scan, IN PLACE: finalH -> s_in ----------------
__global__ __launch_bounds__(256) void inter_kernel(
    const float* __restrict__ totalA, float* __restrict__ buf)
{
    const int tid = blockIdx.x * 256 + threadIdx.x;  // (hh*NM+m)*ND + d
    const int d  = tid & 63;
    const int hm = tid >> 6;                         // 0..255
    float sr = 0.f, si = 0.f;
#pragma unroll
    for (int g = 0; g < NC; ++g) {
        const int e    = g * 256 + hm;
        const int fidx = e * ND + d;
        const float fr = buf[2 * fidx];
        const float fi = buf[2 * fidx + 1];
        buf[2 * fidx]     = sr;
        buf[2 * fidx + 1] = si;
        const float ar = totalA[2 * e];
        const float ai = totalA[2 * e + 1];
        const float nsr = ar * sr - ai * si + fr;
        si = ar * si + ai * sr + fi;
        sr = nsr;
    }
}

// ---------------- Kernel 3: fused recompute + correction, 2 m-rows per wave -> Y ----------------
__global__ __launch_bounds__(256) void final_kernel(
    const float* __restrict__ A_bar, const float* __restrict__ K,
    const float* __restrict__ V, const float* __restrict__ beta,
    const float* __restrict__ s_in, float* __restrict__ Y)
{
    __shared__ float K_lds[NCH][ND], A_lds[NCH][ND], V_lds[NCH][ND], b_lds[NCH];
    const int w  = blockIdx.x * 4 + (threadIdx.x >> 6);
    const int p  = w & 15;
    const int hh = (w >> 4) & (NH - 1);
    const int g  = w >> 7;
    const int lane = threadIdx.x & 63;

    stage_chunk(A_bar, K, V, beta, g, hh, K_lds, A_lds, V_lds, b_lds);

    const int base = (g * NH + hh) * NM;
    const int f0 = (base + p) * ND + lane;
    const int f1 = (base + p + 16) * ND + lane;
    float hr0 = 0.f, hi0 = 0.f, hr1 = 0.f, hi1 = 0.f;
    float zr0 = s_in[2 * f0], zi0 = s_in[2 * f0 + 1];
    float zr1 = s_in[2 * f1], zi1 = s_in[2 * f1 + 1];
    float cr0 = 1.f, ci0 = 0.f, cr1 = 1.f, ci1 = 0.f;
    const int base_l = g * NCH;

#pragma unroll 4
    for (int t = 0; t < NCH; ++t) {
        const float  kd = K_lds[t][lane];
        const float  b  = b_lds[t];
        const float2 a0 = *(const float2*)(&A_lds[t][2 * p]);
        const float2 v0 = *(const float2*)(&V_lds[t][2 * p]);
        const float2 a1 = *(const float2*)(&A_lds[t][2 * (p + 16)]);
        const float2 v1 = *(const float2*)(&V_lds[t][2 * (p + 16)]);
        const float  bk = b * kd;

        const float hkr0 = wave_sum_bcast(hr0 * kd);
        const float hki0 = wave_sum_bcast(hi0 * kd);
        const float zkr0 = wave_sum_bcast(zr0 * kd);
        const float zki0 = wave_sum_bcast(zi0 * kd);
        const float hkr1 = wave_sum_bcast(hr1 * kd);
        const float hki1 = wave_sum_bcast(hi1 * kd);
        const float zkr1 = wave_sum_bcast(zr1 * kd);
        const float zki1 = wave_sum_bcast(zi1 * kd);

        const float tr0 = hr0 - bk * hkr0, ti0 = hi0 - bk * hki0;
        hr0 = a0.x * tr0 - a0.y * ti0 + bk * v0.x;
        hi0 = a0.x * ti0 + a0.y * tr0 + bk * v0.y;
        zr0 -= bk * zkr0;  zi0 -= bk * zki0;

        const float tr1 = hr1 - bk * hkr1, ti1 = hi1 - bk * hki1;
        hr1 = a1.x * tr1 - a1.y * ti1 + bk * v1.x;
        hi1 = a1.x * ti1 + a1.y * tr1 + bk * v1.y;
        zr1 -= bk * zkr1;  zi1 -= bk * zki1;

        float n;
        n = cr0 * a0.x - ci0 * a0.y; ci0 = cr0 * a0.y + ci0 * a0.x; cr0 = n;
        n = cr1 * a1.x - ci1 * a1.y; ci1 = cr1 * a1.y + ci1 * a1.x; cr1 = n;

        const float yr0 = hr0 + cr0 * zr0 - ci0 * zi0;
        const float yi0 = hi0 + cr0 * zi0 + ci0 * zr0;
        const float yr1 = hr1 + cr1 * zr1 - ci1 * zi1;
        const float yi1 = hi1 + cr1 * zi1 + ci1 * zr1;

        // Y[b,l,h,2m,d]=Re, Y[b,l,h,2m+1,d]=Im
        const int ybase = ((base_l + t) * NH + hh) * (2 * NM) * ND + lane;
        __builtin_nontemporal_store(yr0, &Y[ybase + (2 * p) * ND]);
        __builtin_nontemporal_store(yi0, &Y[ybase + (2 * p + 1) * ND]);
        __builtin_nontemporal_store(yr1, &Y[ybase + (2 * (p + 16)) * ND]);
        __builtin_nontemporal_store(yi1, &Y[ybase + (2 * (p + 16) + 1) * ND]);
    }
}

extern "C" void kernel_launch(void* const* d_in, const int* in_sizes, int n_in,
                              void* d_out, int out_size, void* d_ws, size_t ws_size,
                              hipStream_t stream) {
    const float* A_bar = (const float*)d_in[0];
    const float* K     = (const float*)d_in[1];
    const float* V     = (const float*)d_in[2];
    const float* beta  = (const float*)d_in[3];
    float* Y = (float*)d_out;

    float* ws = (float*)d_ws;
    float* totalA = ws;                         // NC*NH*NM*2 = 16384 floats
    float* buf    = ws + 16384;                 // finalH/s_in in place: 1,048,576 floats

    const int nwave = NC * NH * (NM / 2);       // 4096 pair-waves
    intra_kernel<<<nwave / 4, 256, 0, stream>>>(A_bar, K, V, beta, totalA, buf);
    inter_kernel<<<(NH * NM * ND) / 256, 256, 0, stream>>>(totalA, buf);
    final_kernel<<<nwave / 4, 256, 0, stream>>>(A_bar, K, V, beta, buf, Y);
}

// Round 7
// 57.214 us; speedup vs baseline: 2.4389x; 1.2244x over previous
//
#include <hip/hip_runtime.h>

#define NH 8
#define ND 64
#define NM 32
#define NCH 32   // sub-chunk size (re-chunked; math is associative)
#define NC 32    // num sub-chunks

// Full-wave (64-lane) sum reduction using DPP on the VALU pipe.
__device__ __forceinline__ float wave_sum_bcast(float x) {
    float s = x;
    s += __int_as_float(__builtin_amdgcn_update_dpp(0, __float_as_int(s), 0x111, 0xf, 0xf, false));
    s += __int_as_float(__builtin_amdgcn_update_dpp(0, __float_as_int(s), 0x112, 0xf, 0xf, false));
    s += __int_as_float(__builtin_amdgcn_update_dpp(0, __float_as_int(s), 0x114, 0xf, 0xf, false));
    s += __int_as_float(__builtin_amdgcn_update_dpp(0, __float_as_int(s), 0x118, 0xf, 0xf, false));
    s += __int_as_float(__builtin_amdgcn_update_dpp(0, __float_as_int(s), 0x142, 0xa, 0xf, false));
    s += __int_as_float(__builtin_amdgcn_update_dpp(0, __float_as_int(s), 0x143, 0xc, 0xf, false));
    return __int_as_float(__builtin_amdgcn_readlane(__float_as_int(s), 63));
}

// Cooperative stage of one (g,hh) chunk into LDS. Block = 256 threads.
__device__ __forceinline__ void stage_chunk(
    const float* __restrict__ A_bar, const float* __restrict__ K,
    const float* __restrict__ V, const float* __restrict__ beta,
    int g, int hh,
    float (*K_lds)[ND], float (*A_lds)[ND], float (*V_lds)[ND], float* b_lds)
{
    const int tid = threadIdx.x;              // 256 threads
    const int t   = tid >> 3;                 // 0..31
    const int i   = tid & 7;                  // 0..7 -> 8 floats each
    const int l   = g * NCH + t;
    const int row = (l * NH + hh) * 64;
    const float4 k4a = *(const float4*)(K + row + i * 8);
    const float4 k4b = *(const float4*)(K + row + i * 8 + 4);
    const float4 a4a = *(const float4*)(A_bar + row + i * 8);
    const float4 a4b = *(const float4*)(A_bar + row + i * 8 + 4);
    const float4 v4a = *(const float4*)(V + row + i * 8);
    const float4 v4b = *(const float4*)(V + row + i * 8 + 4);
    *(float4*)(&K_lds[t][i * 8])     = k4a;
    *(float4*)(&K_lds[t][i * 8 + 4]) = k4b;
    *(float4*)(&A_lds[t][i * 8])     = a4a;
    *(float4*)(&A_lds[t][i * 8 + 4]) = a4b;
    *(float4*)(&V_lds[t][i * 8])     = v4a;
    *(float4*)(&V_lds[t][i * 8 + 4]) = v4b;
    if (tid < NCH) b_lds[tid] = beta[(g * NCH + tid) * NH + hh];
    __syncthreads();
}

// ---------------- Kernel 1: intra scan, 2 m-rows per wave -> totalA, finalH ----------------
__global__ __launch_bounds__(256) void intra_kernel(
    const float* __restrict__ A_bar, const float* __restrict__ K,
    const float* __restrict__ V, const float* __restrict__ beta,
    float* __restrict__ totalA, float* __restrict__ finalH)
{
    __shared__ float K_lds[NCH][ND], A_lds[NCH][ND], V_lds[NCH][ND], b_lds[NCH];
    const int w  = blockIdx.x * 4 + (threadIdx.x >> 6);  // pair-wave id
    const int p  = w & 15;                               // m0 = p, m1 = p+16
    const int hh = (w >> 4) & (NH - 1);
    const int g  = w >> 7;
    const int lane = threadIdx.x & 63;

    stage_chunk(A_bar, K, V, beta, g, hh, K_lds, A_lds, V_lds, b_lds);

    float hr0 = 0.f, hi0 = 0.f, hr1 = 0.f, hi1 = 0.f;
    float cr0 = 1.f, ci0 = 0.f, cr1 = 1.f, ci1 = 0.f;

#pragma unroll 4
    for (int t = 0; t < NCH; ++t) {
        const float  kd  = K_lds[t][lane];
        const float  b   = b_lds[t];
        const float2 a0  = *(const float2*)(&A_lds[t][2 * p]);
        const float2 v0  = *(const float2*)(&V_lds[t][2 * p]);
        const float2 a1  = *(const float2*)(&A_lds[t][2 * (p + 16)]);
        const float2 v1  = *(const float2*)(&V_lds[t][2 * (p + 16)]);
        const float  bk  = b * kd;

        const float hkr0 = wave_sum_bcast(hr0 * kd);
        const float hki0 = wave_sum_bcast(hi0 * kd);
        const float hkr1 = wave_sum_bcast(hr1 * kd);
        const float hki1 = wave_sum_bcast(hi1 * kd);

        const float tr0 = hr0 - bk * hkr0, ti0 = hi0 - bk * hki0;
        hr0 = a0.x * tr0 - a0.y * ti0 + bk * v0.x;
        hi0 = a0.x * ti0 + a0.y * tr0 + bk * v0.y;
        const float tr1 = hr1 - bk * hkr1, ti1 = hi1 - bk * hki1;
        hr1 = a1.x * tr1 - a1.y * ti1 + bk * v1.x;
        hi1 = a1.x * ti1 + a1.y * tr1 + bk * v1.y;

        float n;
        n = cr0 * a0.x - ci0 * a0.y; ci0 = cr0 * a0.y + ci0 * a0.x; cr0 = n;
        n = cr1 * a1.x - ci1 * a1.y; ci1 = cr1 * a1.y + ci1 * a1.x; cr1 = n;
    }

    const int base = (g * NH + hh) * NM;
    const int f0 = (base + p) * ND + lane;
    const int f1 = (base + p + 16) * ND + lane;
    finalH[2 * f0]     = hr0;  finalH[2 * f0 + 1] = hi0;
    finalH[2 * f1]     = hr1;  finalH[2 * f1 + 1] = hi1;
    if (lane == 0) {
        totalA[2 * (base + p)]          = cr0;
        totalA[2 * (base + p) + 1]      = ci0;
        totalA[2 * (base + p + 16)]     = cr1;
        totalA[2 * (base + p + 16) + 1] = ci1;
    }
}

// ---------------- Kernel 2: inter-chunk serial scan, IN PLACE: finalH -> s_in ----------------
__global__ __launch_bounds__(256) void inter_kernel(
    const float* __restrict__ totalA, float* __restrict__ buf)
{
    const int tid = blockIdx.x * 256 + threadIdx.x;  // (hh*NM+m)*ND + d
    const int d  = tid & 63;
    const int hm = tid >> 6;                         // 0..255
    float sr = 0.f, si = 0.f;
#pragma unroll
    for (int g = 0; g < NC; ++g) {
        const int e    = g * 256 + hm;
        const int fidx = e * ND + d;
        const float fr = buf[2 * fidx];
        const float fi = buf[2 * fidx + 1];
        buf[2 * fidx]     = sr;
        buf[2 * fidx + 1] = si;
        const float ar = totalA[2 * e];
        const float ai = totalA[2 * e + 1];
        const float nsr = ar * sr - ai * si + fr;
        si = ar * si + ai * sr + fi;
        sr = nsr;
    }
}

// ---------------- Kernel 3: fused scan, state IS the output ----------------
// y_t = h_t + cumA_t * z_t satisfies the SAME recurrence as h with init = s_in.
__global__ __launch_bounds__(256) void final_kernel(
    const float* __restrict__ A_bar, const float* __restrict__ K,
    const float* __restrict__ V, const float* __restrict__ beta,
    const float* __restrict__ s_in, float* __restrict__ Y)
{
    __shared__ float K_lds[NCH][ND], A_lds[NCH][ND], V_lds[NCH][ND], b_lds[NCH];
    const int w  = blockIdx.x * 4 + (threadIdx.x >> 6);
    const int p  = w & 15;
    const int hh = (w >> 4) & (NH - 1);
    const int g  = w >> 7;
    const int lane = threadIdx.x & 63;

    stage_chunk(A_bar, K, V, beta, g, hh, K_lds, A_lds, V_lds, b_lds);

    const int base = (g * NH + hh) * NM;
    const int f0 = (base + p) * ND + lane;
    const int f1 = (base + p + 16) * ND + lane;
    float hr0 = s_in[2 * f0], hi0 = s_in[2 * f0 + 1];
    float hr1 = s_in[2 * f1], hi1 = s_in[2 * f1 + 1];
    const int base_l = g * NCH;

#pragma unroll 4
    for (int t = 0; t < NCH; ++t) {
        const float  kd = K_lds[t][lane];
        const float  b  = b_lds[t];
        const float2 a0 = *(const float2*)(&A_lds[t][2 * p]);
        const float2 v0 = *(const float2*)(&V_lds[t][2 * p]);
        const float2 a1 = *(const float2*)(&A_lds[t][2 * (p + 16)]);
        const float2 v1 = *(const float2*)(&V_lds[t][2 * (p + 16)]);
        const float  bk = b * kd;

        const float hkr0 = wave_sum_bcast(hr0 * kd);
        const float hki0 = wave_sum_bcast(hi0 * kd);
        const float hkr1 = wave_sum_bcast(hr1 * kd);
        const float hki1 = wave_sum_bcast(hi1 * kd);

        const float tr0 = hr0 - bk * hkr0, ti0 = hi0 - bk * hki0;
        hr0 = a0.x * tr0 - a0.y * ti0 + bk * v0.x;
        hi0 = a0.x * ti0 + a0.y * tr0 + bk * v0.y;
        const float tr1 = hr1 - bk * hkr1, ti1 = hi1 - bk * hki1;
        hr1 = a1.x * tr1 - a1.y * ti1 + bk * v1.x;
        hi1 = a1.x * ti1 + a1.y * tr1 + bk * v1.y;

        // Y[b,l,h,2m,d]=Re, Y[b,l,h,2m+1,d]=Im — state IS the output
        const int ybase = ((base_l + t) * NH + hh) * (2 * NM) * ND + lane;
        __builtin_nontemporal_store(hr0, &Y[ybase + (2 * p) * ND]);
        __builtin_nontemporal_store(hi0, &Y[ybase + (2 * p + 1) * ND]);
        __builtin_nontemporal_store(hr1, &Y[ybase + (2 * (p + 16)) * ND]);
        __builtin_nontemporal_store(hi1, &Y[ybase + (2 * (p + 16) + 1) * ND]);
    }
}

extern "C" void kernel_launch(void* const* d_in, const int* in_sizes, int n_in,
                              void* d_out, int out_size, void* d_ws, size_t ws_size,
                              hipStream_t stream) {
    const float* A_bar = (const float*)d_in[0];
    const float* K     = (const float*)d_in[1];
    const float* V     = (const float*)d_in[2];
    const float* beta  = (const float*)d_in[3];
    float* Y = (float*)d_out;

    float* ws = (float*)d_ws;
    float* totalA = ws;                         // NC*NH*NM*2 = 16384 floats
    float* buf    = ws + 16384;                 // finalH/s_in in place: 1,048,576 floats

    const int nwave = NC * NH * (NM / 2);       // 4096 pair-waves
    intra_kernel<<<nwave / 4, 256, 0, stream>>>(A_bar, K, V, beta, totalA, buf);
    inter_kernel<<<(NH * NM * ND) / 256, 256, 0, stream>>>(totalA, buf);
    final_kernel<<<nwave / 4, 256, 0, stream>>>(A_bar, K, V, beta, buf, Y);
}